// Round 1
// baseline (84.255 us; speedup 1.0000x reference)
//
#include <hip/hip_runtime.h>
#include <hip/hip_fp16.h>

// out[i,j] = sum_k relu(a@feats^T)[i,k] * ((b@feats^T)[j,k] <= 0)
// Na=Nb=1024, D=512, K=256.
//
// Pipeline (all matrix-core, no f32 vector GEMM, no K-split partials):
//  k0 convert: split f32 -> f16 hi/lo planes.  x = hi + lo/2048 with
//              hi = f16(x), lo = f16((x-hi)*2048)  (scaling avoids f16 denorms;
//              (x - hi) is exact in f32).
//  k1 stage1 : MFMA f16 16x16x32.
//              a-rows: p = relu(ah.fh)            (err ~0.01 abs, better than the
//                                                 old bf16 rounding of p ~0.09)
//              b-rows: v = ah.fh + (ah.fl + al.fh)/2048  -> mask = (v<=0)
//                      err sigma ~1e-5: same class as an f32 GEMM's deviation
//                      from the XLA reference, so mask-flip exposure unchanged.
//  k2 gemm2  : out = p @ m^T, f16 MFMA (same verified frag layout as bf16).

typedef _Float16 f16;
typedef _Float16 f16x8 __attribute__((ext_vector_type(8)));
typedef _Float16 f16x4 __attribute__((ext_vector_type(4)));
typedef float    f32x4 __attribute__((ext_vector_type(4)));

// ---------------------------------------------------------------- k0: convert
__global__ __launch_bounds__(256) void convert_kernel(
    const float* __restrict__ a, const float* __restrict__ b,
    const float* __restrict__ feats,
    f16* __restrict__ Xh, f16* __restrict__ Xl,
    f16* __restrict__ Fh, f16* __restrict__ Fl)
{
    // 2304 rows (1024 a, 1024 b, 256 feats) x 512 cols, 4 f32/thread.
    // grid = 2304*512/4/256 = 1152 blocks.
    const int g   = blockIdx.x * 256 + threadIdx.x;   // 0..294911
    const int row = g >> 7;                           // 0..2303
    const int c4  = (g & 127) * 4;                    // 0..508

    const float* src;
    f16 *oh, *ol;
    if (row < 1024) {
        src = a + (size_t)row * 512 + c4;
        oh = Xh + (size_t)row * 512 + c4;  ol = Xl + (size_t)row * 512 + c4;
    } else if (row < 2048) {
        src = b + (size_t)(row - 1024) * 512 + c4;
        oh = Xh + (size_t)row * 512 + c4;  ol = Xl + (size_t)row * 512 + c4;
    } else {
        const int r = row - 2048;
        src = feats + (size_t)r * 512 + c4;
        oh = Fh + (size_t)r * 512 + c4;    ol = Fl + (size_t)r * 512 + c4;
    }

    float4 v = *(const float4*)src;
    float vv[4] = {v.x, v.y, v.z, v.w};
    f16x4 h, l;
    #pragma unroll
    for (int i = 0; i < 4; i++) {
        f16 hi = (f16)vv[i];
        float r = vv[i] - (float)hi;        // exact in f32
        h[i] = hi;
        l[i] = (f16)(r * 2048.0f);          // scaled residual, no denorms
    }
    *(f16x4*)oh = h;
    *(f16x4*)ol = l;
}

// ---------------------------------------------------------------- k1: stage1
__global__ __launch_bounds__(512) void stage1_kernel(
    const f16* __restrict__ Xh, const f16* __restrict__ Xl,
    const f16* __restrict__ Fh, const f16* __restrict__ Fl,
    f16* __restrict__ P, f16* __restrict__ M)
{
    // Block tile 32(m) x 64(n), 8 waves as 2(m) x 4(n), wave tile 16x16.
    // grid = (2048/32) * (256/64) = 256 blocks, 1/CU, 2 waves/SIMD.
    // Fragments loaded straight from global: Fh/Fl are 0.5 MB (L2-resident),
    // X rows are read by exactly 4 n-tiles; duplicate frag loads within a
    // block hit L1.
    const int mt = blockIdx.x >> 2;     // 0..63
    const int nt = blockIdx.x & 3;      // 0..3
    const int m0 = mt * 32;             // combined [a;b] row
    const int n0 = nt * 64;

    const int tid  = threadIdx.x;
    const int w    = tid >> 6;          // 0..7
    const int lane = tid & 63;
    const int wr   = w >> 2;            // 0..1
    const int wc   = w & 3;             // 0..3
    const int l15  = lane & 15;
    const int q    = lane >> 4;         // 0..3

    const int arow = m0 + wr * 16 + l15;          // A frag: row = lane&15
    const int brow = n0 + wc * 16 + l15;          // B frag: feats row -> out col

    const f16* pa_h = Xh + (size_t)arow * 512 + q * 8;
    const f16* pa_l = Xl + (size_t)arow * 512 + q * 8;
    const f16* pf_h = Fh + (size_t)brow * 512 + q * 8;
    const f16* pf_l = Fl + (size_t)brow * 512 + q * 8;

    f32x4 acc1  = {0.f, 0.f, 0.f, 0.f};

    if (m0 >= 1024) {   // b-rows: accurate sign via 3-product f16 split
        f32x4 acc2a = {0.f, 0.f, 0.f, 0.f};
        f32x4 acc2b = {0.f, 0.f, 0.f, 0.f};
        #pragma unroll
        for (int c = 0; c < 16; c++) {            // D=512, 16 chunks of K=32
            f16x8 ah = *(const f16x8*)(pa_h + c * 32);
            f16x8 al = *(const f16x8*)(pa_l + c * 32);
            f16x8 fh = *(const f16x8*)(pf_h + c * 32);
            f16x8 fl = *(const f16x8*)(pf_l + c * 32);
            acc1  = __builtin_amdgcn_mfma_f32_16x16x32_f16(ah, fh, acc1,  0, 0, 0);
            acc2a = __builtin_amdgcn_mfma_f32_16x16x32_f16(ah, fl, acc2a, 0, 0, 0);
            acc2b = __builtin_amdgcn_mfma_f32_16x16x32_f16(al, fh, acc2b, 0, 0, 0);
        }
        // C/D layout: col = lane&15, row = (lane>>4)*4 + r
        const int orow0 = (m0 - 1024) + wr * 16 + q * 4;
        const int ocol  = n0 + wc * 16 + l15;
        #pragma unroll
        for (int r = 0; r < 4; r++) {
            float v = acc1[r] + (acc2a[r] + acc2b[r]) * (1.0f / 2048.0f);
            M[(size_t)(orow0 + r) * 256 + ocol] = (f16)((v <= 0.0f) ? 1.0f : 0.0f);
        }
    } else {            // a-rows: hi product only; p tolerance dominated by store
        #pragma unroll
        for (int c = 0; c < 16; c++) {
            f16x8 ah = *(const f16x8*)(pa_h + c * 32);
            f16x8 fh = *(const f16x8*)(pf_h + c * 32);
            acc1 = __builtin_amdgcn_mfma_f32_16x16x32_f16(ah, fh, acc1, 0, 0, 0);
        }
        const int orow0 = m0 + wr * 16 + q * 4;
        const int ocol  = n0 + wc * 16 + l15;
        #pragma unroll
        for (int r = 0; r < 4; r++) {
            float v = fmaxf(acc1[r], 0.0f);
            P[(size_t)(orow0 + r) * 256 + ocol] = (f16)v;
        }
    }
}

// ---------------------------------------------------------------- k2: gemm2
__global__ __launch_bounds__(256) void gemm2_kernel(
    const f16* __restrict__ p, const f16* __restrict__ m,
    float* __restrict__ out)
{
    // out (1024x1024) = p (1024x256) @ m^T (1024x256 row-major, contract k).
    // Block tile 32(i) x 64(j); 4 waves 2x2; wave tile 16x32. grid = 512.
    const int bi = blockIdx.x >> 4;      // 0..31
    const int bj = blockIdx.x & 15;      // 0..15
    const int i0 = bi * 32;
    const int j0 = bj * 64;

    const int tid  = threadIdx.x;
    const int w    = tid >> 6;           // 0..3
    const int lane = tid & 63;
    const int wi = w >> 1;               // 0..1
    const int wj = w & 1;                // 0..1

    const int l15 = lane & 15;
    const int q   = lane >> 4;           // 0..3

    const int arow  = i0 + wi * 16 + l15;
    const int jbase = j0 + wj * 32;
    const int brow0 = jbase + l15;
    const int brow1 = brow0 + 16;

    f32x4 acc0 = {0.f, 0.f, 0.f, 0.f};
    f32x4 acc1 = {0.f, 0.f, 0.f, 0.f};

    #pragma unroll
    for (int k0 = 0; k0 < 256; k0 += 32) {
        const int ko = k0 + q * 8;
        f16x8 av = *(const f16x8*)(p + (size_t)arow  * 256 + ko);
        f16x8 b0 = *(const f16x8*)(m + (size_t)brow0 * 256 + ko);
        f16x8 b1 = *(const f16x8*)(m + (size_t)brow1 * 256 + ko);
        acc0 = __builtin_amdgcn_mfma_f32_16x16x32_f16(av, b0, acc0, 0, 0, 0);
        acc1 = __builtin_amdgcn_mfma_f32_16x16x32_f16(av, b1, acc1, 0, 0, 0);
    }

    const int orow = i0 + wi * 16 + q * 4;
    const int ocol = jbase + l15;
    #pragma unroll
    for (int r = 0; r < 4; r++) {
        out[(size_t)(orow + r) * 1024 + ocol]      = acc0[r];
        out[(size_t)(orow + r) * 1024 + ocol + 16] = acc1[r];
    }
}

extern "C" void kernel_launch(void* const* d_in, const int* in_sizes, int n_in,
                              void* d_out, int out_size, void* d_ws, size_t ws_size,
                              hipStream_t stream) {
    const float* a     = (const float*)d_in[0];   // 1024x512
    const float* b     = (const float*)d_in[1];   // 1024x512
    const float* feats = (const float*)d_in[2];   // 256x512
    float* out = (float*)d_out;                   // 1024x1024

    // workspace layout (f16 planes), 5.5 MB total
    f16* Xh = (f16*)d_ws;               // 2048*512 = 2 MB
    f16* Xl = Xh + (size_t)2048 * 512;  // 2 MB
    f16* Fh = Xl + (size_t)2048 * 512;  // 256*512 = 0.25 MB
    f16* Fl = Fh + (size_t)256 * 512;   // 0.25 MB
    f16* P  = Fl + (size_t)256 * 512;   // 1024*256 = 0.5 MB
    f16* M  = P  + (size_t)1024 * 256;  // 0.5 MB

    convert_kernel<<<1152, 256, 0, stream>>>(a, b, feats, Xh, Xl, Fh, Fl);
    stage1_kernel <<< 256, 512, 0, stream>>>(Xh, Xl, Fh, Fl, P, M);
    gemm2_kernel  <<< 512, 256, 0, stream>>>(P, M, out);
}